// Round 20
// baseline (212.663 us; speedup 1.0000x reference)
//
#include <hip/hip_runtime.h>
#include <cstdint>

#define NN 8192
#define NT 16384         // 2 batches merged: total rows
#define EE 131072
#define EPAD (EE + NN)   // edges + self loops = 139264
#define SPAD (EPAD + 3 * NN)  // 4-aligned padded CSR capacity
#define FIN 128
#define CH 512           // H*HID = H*OUT
#define NH 8
#define NEG 0.2f

typedef __attribute__((ext_vector_type(8))) short short8;
typedef __attribute__((ext_vector_type(4))) unsigned short u16x4;
typedef __attribute__((ext_vector_type(4))) float f32x4;
typedef __attribute__((ext_vector_type(4))) int i32x4;

__device__ inline unsigned short bf16rne(float x) {
    unsigned u = __float_as_uint(x);
    unsigned r = (u + 0x7FFFu + ((u >> 16) & 1u)) >> 16;
    return (unsigned short)r;
}
__device__ inline float bf16tof(unsigned short h) {
    return __uint_as_float((unsigned)h << 16);
}
__device__ inline void gload16(const void* g, void* l) {
    __builtin_amdgcn_global_load_lds((const __attribute__((address_space(1))) void*)g,
                                     (__attribute__((address_space(3))) void*)l, 16, 0, 0);
}
// cross-lane add via DPP (VALU only, no DS crossbar). CTRL: 0xB1=quad_perm
// xor1, 0x4E=quad_perm xor2, 0x124=row_ror:4, 0x128=row_ror:8.
template <int CTRL>
__device__ inline float dpp_add(float x) {
    int v = __builtin_amdgcn_update_dpp(0, __float_as_int(x), CTRL, 0xF, 0xF, true);
    return x + __int_as_float(v);
}

// ---------- CSR build (4-aligned padded segments) ----------

__global__ __launch_bounds__(256) void k_deg(const int* __restrict__ ei, int* __restrict__ deg) {
    int e = blockIdx.x * 256 + threadIdx.x;
    if (e >= EPAD) return;
    int dst = (e < EE) ? ei[EE + e] : (e - EE);
    atomicAdd(&deg[dst], 1);
}

// log-depth scan (wave shfl_up + wave-total scan)
__global__ __launch_bounds__(1024) void k_scan(const int* __restrict__ deg, int* __restrict__ rowptr) {
    __shared__ int wsum[16];
    int t = threadIdx.x;
    int lane = t & 63, wid = t >> 6;
    int loc[8];
    int s = 0;
#pragma unroll
    for (int i = 0; i < 8; i++) { loc[i] = s; s += (deg[t * 8 + i] + 3) & ~3; }
    int inc = s;
#pragma unroll
    for (int off = 1; off < 64; off <<= 1) {
        int v = __shfl_up(inc, off);
        if (lane >= off) inc += v;
    }
    if (lane == 63) wsum[wid] = inc;
    __syncthreads();
    if (wid == 0 && lane < 16) {
        int v = wsum[lane];
#pragma unroll
        for (int off = 1; off < 16; off <<= 1) {
            int u = __shfl_up(v, off);
            if (lane >= off) v += u;
        }
        wsum[lane] = v;
    }
    __syncthreads();
    int wbase = (wid == 0) ? 0 : wsum[wid - 1];
    int base = wbase + inc - s;          // exclusive prefix for this thread
#pragma unroll
    for (int i = 0; i < 8; i++) rowptr[t * 8 + i] = base + loc[i];
    if (t == 1023) rowptr[NN] = wbase + inc;
}

__global__ __launch_bounds__(256) void k_scatter(const int* __restrict__ ei, const int* __restrict__ rowptr,
                                                 int* __restrict__ cursor, int* __restrict__ ssrc) {
    int e = blockIdx.x * 256 + threadIdx.x;
    if (e >= EPAD) return;
    int src = (e < EE) ? ei[e] : (e - EE);
    int dst = (e < EE) ? ei[EE + e] : (e - EE);
    int pos = rowptr[dst] + atomicAdd(&cursor[dst], 1);
    ssrc[pos] = src;
}

// fill pad slots with src=0 (row 0 gather, masked out of softmax)
__global__ __launch_bounds__(256) void k_pad(const int* __restrict__ rowptr, const int* __restrict__ deg,
                                             int* __restrict__ ssrc) {
    int n = blockIdx.x * 256 + threadIdx.x;
    if (n >= NN) return;
    int e = rowptr[n] + deg[n], pe = rowptr[n + 1];
    for (int i = e; i < pe; i++) ssrc[i] = 0;
}

// ---------- conversions ----------

__global__ __launch_bounds__(256) void k_cvt_ah(const float* __restrict__ F,
                                                unsigned short* __restrict__ Ah, int n4) {
    int i = blockIdx.x * 256 + threadIdx.x;
    if (i >= n4) return;
    f32x4 v = ((const f32x4*)F)[i];
#pragma unroll
    for (int c = 0; c < 4; c++) Ah[i * 4 + c] = bf16rne(v[c]);
}

// W[K][512] (Wl,Wr) -> Wt[n=1024][K] bf16-hi (transposed, K contiguous)
template <int K>
__global__ __launch_bounds__(256) void k_cvt_w(const float* __restrict__ Wl, const float* __restrict__ Wr,
                                               unsigned short* __restrict__ Wh) {
    int idx = blockIdx.x * 256 + threadIdx.x;   // = n*K + k
    int n = idx / K, k = idx % K;
    const float* W = (n < 512) ? Wl : Wr;
    Wh[idx] = bf16rne(W[k * 512 + (n & 511)]);
}

// ---------- bf16 MFMA GEMM: [NT x K] @ [K x 1024] -> XLb | XRb (both bf16) ----------
// A and B bf16-hi (B-lo below the bf16 output rounding floor, r15/r18).
// XR now ALSO bf16: it only feeds the logits (error ~2^-9, negligible);
// halves GEMM write traffic and node XR-row reads. BK=64 single-buffer loop.

template <int K, int BK>
__global__ __launch_bounds__(256) void k_gemm_mfma(const unsigned short* __restrict__ Ah,
                                                   const unsigned short* __restrict__ Bh,
                                                   unsigned short* __restrict__ XLb,
                                                   unsigned short* __restrict__ XRb) {
    const int NS = BK / 8;               // kh slices per slab
    __shared__ unsigned short sAh[NS][128][8], sBh[NS][128][8];
    int tid = threadIdx.x;
    int l = tid & 63;
    int w = tid >> 6, wm = w >> 1, wn = w & 1;
    int m0 = blockIdx.x * 128, n0 = blockIdx.y * 128;
    int lr = l & 15, kh = l >> 4;
    f32x4 acc[4][4] = {};

    for (int k0 = 0; k0 < K; k0 += BK) {
#pragma unroll
        for (int g = 0; g < NS / 2; g++) {
            int cell = g * 256 + tid;
            int ckh = cell >> 7, cr = cell & 127;
            int ka = k0 + ckh * 8;
            gload16(Ah + (size_t)(m0 + cr) * K + ka, &sAh[ckh][cr][0]);
            gload16(Bh + (size_t)(n0 + cr) * K + ka, &sBh[ckh][cr][0]);
        }
        __syncthreads();
#pragma unroll
        for (int kk = 0; kk < BK / 32; kk++) {
            int ks = kk * 4 + kh;
            short8 fah[4], fbh[4];
#pragma unroll
            for (int i = 0; i < 4; i++) {
                fah[i] = *(const short8*)&sAh[ks][wm * 64 + i * 16 + lr][0];
                fbh[i] = *(const short8*)&sBh[ks][wn * 64 + i * 16 + lr][0];
            }
#pragma unroll
            for (int i = 0; i < 4; i++)
#pragma unroll
                for (int j = 0; j < 4; j++)
                    acc[i][j] = __builtin_amdgcn_mfma_f32_16x16x32_bf16(fah[i], fbh[j], acc[i][j], 0, 0, 0);
        }
        __syncthreads();
    }
    // C/D layout: col = lane&15, row = (lane>>4)*4 + q  [m89-verified]
    int colt = n0 + wn * 64;     // wave-uniform
    int cb = colt & 511;
    unsigned short* O = (colt < 512) ? XLb : XRb;
#pragma unroll
    for (int i = 0; i < 4; i++) {
        int mg = m0 + wm * 64 + i * 16 + kh * 4;
#pragma unroll
        for (int j = 0; j < 4; j++) {
            int cg = cb + j * 16 + lr;
#pragma unroll
            for (int q = 0; q < 4; q++)
                O[(size_t)(mg + q) * CH + cg] = bf16rne(acc[i][j][q]);
        }
    }
}

// ---------- fused per-node: logits + online softmax + aggregation ----------
// r15 structure. 2 consecutive nids per 256-thread block; 2 waves per node
// (head-group g); lane l owns 4 consecutive channels g*256+l*4 (one head).
// 3-deep pipeline over 4-edge chunks. Gathers use 32-BIT BYTE OFFSETS from a
// char* base (saves the 64-bit mul+carry chain per gather). Single
// bf16->f32 convert per value; lrelu = max(t, 0.2t). DPP-only fold;
// per-lane softmax state; defer-rescale THR=8. Tail/pad masked via z=-1e30.

#define GATHER(CX, IV)                                                         \
  {                                                                            \
    CX[0] = *(const u16x4*)(XLgc + (unsigned)(IV[0] << 10));                   \
    CX[1] = *(const u16x4*)(XLgc + (unsigned)(IV[1] << 10));                   \
    CX[2] = *(const u16x4*)(XLgc + (unsigned)(IV[2] << 10));                   \
    CX[3] = *(const u16x4*)(XLgc + (unsigned)(IV[3] << 10));                   \
  }

#define PROCESS(CX, cb)                                                        \
  {                                                                            \
    float f[4][4];                                                             \
    _Pragma("unroll") for (int e = 0; e < 4; e++)                              \
      _Pragma("unroll") for (int r = 0; r < 4; r++)                            \
        f[e][r] = bf16tof(CX[e][r]);                                           \
    float z[4];                                                                \
    _Pragma("unroll") for (int e = 0; e < 4; e++) {                            \
      float s = 0.f;                                                           \
      _Pragma("unroll") for (int r = 0; r < 4; r++) {                          \
        float t = f[e][r] + xrv[r];                                            \
        t = fmaxf(t, NEG * t);                                                 \
        s += t * atv[r];                                                       \
      }                                                                        \
      z[e] = s;                                                                \
    }                                                                          \
    _Pragma("unroll") for (int e = 0; e < 4; e++) {                            \
      z[e] = dpp_add<0xB1>(z[e]);                                              \
      z[e] = dpp_add<0x4E>(z[e]);                                              \
      z[e] = dpp_add<0x124>(z[e]);                                             \
      z[e] = dpp_add<0x128>(z[e]);                                             \
    }                                                                          \
    _Pragma("unroll") for (int e = 1; e < 4; e++)                              \
      if ((cb) + e >= end) z[e] = -1e30f;                                      \
    float mc = fmaxf(fmaxf(z[0], z[1]), fmaxf(z[2], z[3]));                    \
    if (__ballot(mc > mh + 8.f) == 0ULL) {                                     \
      float p0 = __expf(z[0] - mh), p1 = __expf(z[1] - mh);                    \
      float p2 = __expf(z[2] - mh), p3 = __expf(z[3] - mh);                    \
      sh += (p0 + p1) + (p2 + p3);                                             \
      _Pragma("unroll") for (int r = 0; r < 4; r++)                            \
        acc[r] += p0 * f[0][r] + p1 * f[1][r] + p2 * f[2][r] + p3 * f[3][r];   \
    } else {                                                                   \
      float nm = fmaxf(mh, mc);                                                \
      float sc = __expf(mh - nm);                                              \
      float p0 = __expf(z[0] - nm), p1 = __expf(z[1] - nm);                    \
      float p2 = __expf(z[2] - nm), p3 = __expf(z[3] - nm);                    \
      sh = sh * sc + (p0 + p1) + (p2 + p3);                                    \
      mh = nm;                                                                 \
      _Pragma("unroll") for (int r = 0; r < 4; r++)                            \
        acc[r] = acc[r] * sc + p0 * f[0][r] + p1 * f[1][r] + p2 * f[2][r] +    \
                 p3 * f[3][r];                                                 \
    }                                                                          \
  }

template <int WRITE_BF16>
__global__ __launch_bounds__(256) void k_node5(const unsigned short* __restrict__ XLb,
                                               const unsigned short* __restrict__ XRb,
                                               const int* __restrict__ rowptr,
                                               const int* __restrict__ deg,
                                               const int* __restrict__ ssrc,
                                               const float* __restrict__ att,
                                               const float* __restrict__ bias,
                                               float* __restrict__ OUT,
                                               unsigned short* __restrict__ OAh) {
    int w = threadIdx.x >> 6;
    int nid = blockIdx.x * 2 + (w >> 1);   // global row 0..NT-1
    int g = w & 1;                         // head-group: heads g*4 .. g*4+3
    int l = threadIdx.x & 63;
    int node = nid & (NN - 1);
    int beg = rowptr[node], pend = rowptr[node + 1];
    int end = beg + deg[node];
    int hb = g * 256 + l * 4;              // 4 consecutive channels, one head

    const char* XLgc = (const char*)(XLb + (size_t)(nid >> 13) * NN * CH + hb);
    u16x4 xr4 = *(const u16x4*)(XRb + (size_t)nid * CH + hb);
    f32x4 xrv, atv;
    atv = *(const f32x4*)(att + hb);
#pragma unroll
    for (int r = 0; r < 4; r++) xrv[r] = bf16tof(xr4[r]);
    f32x4 acc = {0.f, 0.f, 0.f, 0.f};
    float mh = -1e30f, sh = 0.f;

    i32x4 iA = *(const i32x4*)(ssrc + beg);
    i32x4 iB = iA;
    u16x4 curA[4], curB[4];
    GATHER(curA, iA);
    if (beg + 4 < pend) iB = *(const i32x4*)(ssrc + beg + 4);

    int base = beg;
    while (true) {
        // invariant: curA = data(c), iB = idx(c+1)
        if (base + 4 < pend) GATHER(curB, iB);
        if (base + 8 < pend) iA = *(const i32x4*)(ssrc + base + 8);
        PROCESS(curA, base);
        base += 4;
        if (base >= pend) break;
        // invariant: curB = data(c'), iA = idx(c'+1)
        if (base + 4 < pend) GATHER(curA, iA);
        if (base + 8 < pend) iB = *(const i32x4*)(ssrc + base + 8);
        PROCESS(curB, base);
        base += 4;
        if (base >= pend) break;
    }

    float inv = 1.f / sh;
    f32x4 biasv = *(const f32x4*)(bias + hb);
    size_t ob = (size_t)nid * CH + hb;
    if (WRITE_BF16) {
        u16x4 hv;
#pragma unroll
        for (int r = 0; r < 4; r++) {
            float wv = acc[r] * inv + biasv[r];
            hv[r] = bf16rne(wv);
        }
        *(u16x4*)(OAh + ob) = hv;
    } else {
        f32x4 ov;
#pragma unroll
        for (int r = 0; r < 4; r++) {
            float wv = acc[r] * inv + biasv[r];
            ov[r] = (wv > 0.f) ? wv : (__expf(wv) - 1.f);
        }
        *(f32x4*)(OUT + ob) = ov;
    }
}

// ---------- host ----------

extern "C" void kernel_launch(void* const* d_in, const int* in_sizes, int n_in,
                              void* d_out, int out_size, void* d_ws, size_t ws_size,
                              hipStream_t stream) {
    const float* x    = (const float*)d_in[0];
    const int*   ei   = (const int*)d_in[1];
    const float* W1l  = (const float*)d_in[2];
    const float* W1r  = (const float*)d_in[3];
    const float* att1 = (const float*)d_in[4];
    const float* b1   = (const float*)d_in[5];
    const float* W2l  = (const float*)d_in[6];
    const float* W2r  = (const float*)d_in[7];
    const float* att2 = (const float*)d_in[8];
    const float* b2   = (const float*)d_in[9];
    float* out = (float*)d_out;

    char* ws = (char*)d_ws;
    int* rowptr = (int*)ws;                 // NN+1
    int* cursor = rowptr + NN + 1;          // NN   (zeroed)
    int* deg    = cursor + NN;              // NN   (zeroed)
    int* ssrc   = deg + NN;                 // SPAD (4-aligned padded)
    unsigned short* XLb = (unsigned short*)(((uintptr_t)(ssrc + SPAD) + 255) & ~(uintptr_t)255);
    unsigned short* XRb = XLb + (size_t)NT * CH;
    unsigned short* A_h = XRb + (size_t)NT * CH;   // NT*CH bf16
    unsigned short* W1h = A_h + (size_t)NT * CH;   // 1024*FIN
    unsigned short* W2h = W1h + 1024 * FIN;        // 1024*CH

    hipMemsetAsync(cursor, 0, (size_t)2 * NN * sizeof(int), stream);
    k_deg<<<(EPAD + 255) / 256, 256, 0, stream>>>(ei, deg);
    k_scan<<<1, 1024, 0, stream>>>(deg, rowptr);
    k_scatter<<<(EPAD + 255) / 256, 256, 0, stream>>>(ei, rowptr, cursor, ssrc);
    k_pad<<<NN / 256, 256, 0, stream>>>(rowptr, deg, ssrc);
    k_cvt_w<FIN><<<1024 * FIN / 256, 256, 0, stream>>>(W1l, W1r, W1h);
    k_cvt_w<CH><<<1024 * CH / 256, 256, 0, stream>>>(W2l, W2r, W2h);

    // layer 1 (both batches merged: NT rows)
    k_cvt_ah<<<NT * FIN / 4 / 256, 256, 0, stream>>>(x, A_h, NT * FIN / 4);
    k_gemm_mfma<FIN, 64><<<dim3(NT / 128, 8), 256, 0, stream>>>(A_h, W1h, XLb, XRb);
    k_node5<1><<<NT / 2, 256, 0, stream>>>(XLb, XRb, rowptr, deg, ssrc, att1, b1, nullptr, A_h);
    // layer 2
    k_gemm_mfma<CH, 64><<<dim3(NT / 128, 8), 256, 0, stream>>>(A_h, W2h, XLb, XRb);
    k_node5<0><<<NT / 2, 256, 0, stream>>>(XLb, XRb, rowptr, deg, ssrc, att2, b2, out, nullptr);
}

// Round 21
// 210.840 us; speedup vs baseline: 1.0087x; 1.0087x over previous
//
#include <hip/hip_runtime.h>
#include <cstdint>

#define NN 8192
#define NT 16384         // 2 batches merged: total rows
#define EE 131072
#define EPAD (EE + NN)   // edges + self loops = 139264
#define SPAD (EPAD + 3 * NN)  // 4-aligned padded CSR capacity
#define FIN 128
#define CH 512           // H*HID = H*OUT
#define NH 8
#define NEG 0.2f

typedef __attribute__((ext_vector_type(8))) short short8;
typedef __attribute__((ext_vector_type(4))) unsigned short u16x4;
typedef __attribute__((ext_vector_type(4))) float f32x4;
typedef __attribute__((ext_vector_type(4))) int i32x4;

__device__ inline unsigned short bf16rne(float x) {
    unsigned u = __float_as_uint(x);
    unsigned r = (u + 0x7FFFu + ((u >> 16) & 1u)) >> 16;
    return (unsigned short)r;
}
__device__ inline float bf16tof(unsigned short h) {
    return __uint_as_float((unsigned)h << 16);
}
__device__ inline void gload16(const void* g, void* l) {
    __builtin_amdgcn_global_load_lds((const __attribute__((address_space(1))) void*)g,
                                     (__attribute__((address_space(3))) void*)l, 16, 0, 0);
}
// cross-lane add via DPP (VALU only, no DS crossbar). CTRL: 0xB1=quad_perm
// xor1, 0x4E=quad_perm xor2, 0x124=row_ror:4, 0x128=row_ror:8.
template <int CTRL>
__device__ inline float dpp_add(float x) {
    int v = __builtin_amdgcn_update_dpp(0, __float_as_int(x), CTRL, 0xF, 0xF, true);
    return x + __int_as_float(v);
}

// ---------- CSR build (4-aligned padded segments) ----------

__global__ __launch_bounds__(256) void k_deg(const int* __restrict__ ei, int* __restrict__ deg) {
    int e = blockIdx.x * 256 + threadIdx.x;
    if (e >= EPAD) return;
    int dst = (e < EE) ? ei[EE + e] : (e - EE);
    atomicAdd(&deg[dst], 1);
}

// log-depth scan (wave shfl_up + wave-total scan)
__global__ __launch_bounds__(1024) void k_scan(const int* __restrict__ deg, int* __restrict__ rowptr) {
    __shared__ int wsum[16];
    int t = threadIdx.x;
    int lane = t & 63, wid = t >> 6;
    int loc[8];
    int s = 0;
#pragma unroll
    for (int i = 0; i < 8; i++) { loc[i] = s; s += (deg[t * 8 + i] + 3) & ~3; }
    int inc = s;
#pragma unroll
    for (int off = 1; off < 64; off <<= 1) {
        int v = __shfl_up(inc, off);
        if (lane >= off) inc += v;
    }
    if (lane == 63) wsum[wid] = inc;
    __syncthreads();
    if (wid == 0 && lane < 16) {
        int v = wsum[lane];
#pragma unroll
        for (int off = 1; off < 16; off <<= 1) {
            int u = __shfl_up(v, off);
            if (lane >= off) v += u;
        }
        wsum[lane] = v;
    }
    __syncthreads();
    int wbase = (wid == 0) ? 0 : wsum[wid - 1];
    int base = wbase + inc - s;          // exclusive prefix for this thread
#pragma unroll
    for (int i = 0; i < 8; i++) rowptr[t * 8 + i] = base + loc[i];
    if (t == 1023) rowptr[NN] = wbase + inc;
}

__global__ __launch_bounds__(256) void k_scatter(const int* __restrict__ ei, const int* __restrict__ rowptr,
                                                 int* __restrict__ cursor, int* __restrict__ ssrc) {
    int e = blockIdx.x * 256 + threadIdx.x;
    if (e >= EPAD) return;
    int src = (e < EE) ? ei[e] : (e - EE);
    int dst = (e < EE) ? ei[EE + e] : (e - EE);
    int pos = rowptr[dst] + atomicAdd(&cursor[dst], 1);
    ssrc[pos] = src;
}

// fill pad slots with src=0 (row 0 gather, masked out of softmax)
__global__ __launch_bounds__(256) void k_pad(const int* __restrict__ rowptr, const int* __restrict__ deg,
                                             int* __restrict__ ssrc) {
    int n = blockIdx.x * 256 + threadIdx.x;
    if (n >= NN) return;
    int e = rowptr[n] + deg[n], pe = rowptr[n + 1];
    for (int i = e; i < pe; i++) ssrc[i] = 0;
}

// ---------- conversions ----------

__global__ __launch_bounds__(256) void k_cvt_ah(const float* __restrict__ F,
                                                unsigned short* __restrict__ Ah, int n4) {
    int i = blockIdx.x * 256 + threadIdx.x;
    if (i >= n4) return;
    f32x4 v = ((const f32x4*)F)[i];
#pragma unroll
    for (int c = 0; c < 4; c++) Ah[i * 4 + c] = bf16rne(v[c]);
}

// W[K][512] (Wl,Wr) -> Wt[n=1024][K] bf16-hi (transposed, K contiguous)
template <int K>
__global__ __launch_bounds__(256) void k_cvt_w(const float* __restrict__ Wl, const float* __restrict__ Wr,
                                               unsigned short* __restrict__ Wh) {
    int idx = blockIdx.x * 256 + threadIdx.x;   // = n*K + k
    int n = idx / K, k = idx % K;
    const float* W = (n < 512) ? Wl : Wr;
    Wh[idx] = bf16rne(W[k * 512 + (n & 511)]);
}

// ---------- bf16 MFMA GEMM: [NT x K] @ [K x 1024] -> XLb (bf16) | XR (f32) ----------
// A and B both bf16-hi. B-lo dropped for BOTH layers: layer-1's XL output is
// rounded to bf16 anyway (2^-8 floor), so B-lo polish is below the noise;
// layer-2 verified in r15 (absmax unchanged). BK=64: one barrier pair per
// 64-K slab. Single-buffer m97 loop (dbuf regressed r13; counted-vmcnt
// neutral r19 — structure ceiling per m99/m131 catalog).

template <int K, int BK>
__global__ __launch_bounds__(256) void k_gemm_mfma(const unsigned short* __restrict__ Ah,
                                                   const unsigned short* __restrict__ Bh,
                                                   unsigned short* __restrict__ XLb,
                                                   float* __restrict__ XR) {
    const int NS = BK / 8;               // kh slices per slab
    __shared__ unsigned short sAh[NS][128][8], sBh[NS][128][8];
    int tid = threadIdx.x;
    int l = tid & 63;
    int w = tid >> 6, wm = w >> 1, wn = w & 1;
    int m0 = blockIdx.x * 128, n0 = blockIdx.y * 128;
    int lr = l & 15, kh = l >> 4;
    f32x4 acc[4][4] = {};

    for (int k0 = 0; k0 < K; k0 += BK) {
#pragma unroll
        for (int g = 0; g < NS / 2; g++) {
            int cell = g * 256 + tid;
            int ckh = cell >> 7, cr = cell & 127;
            int ka = k0 + ckh * 8;
            gload16(Ah + (size_t)(m0 + cr) * K + ka, &sAh[ckh][cr][0]);
            gload16(Bh + (size_t)(n0 + cr) * K + ka, &sBh[ckh][cr][0]);
        }
        __syncthreads();
#pragma unroll
        for (int kk = 0; kk < BK / 32; kk++) {
            int ks = kk * 4 + kh;
            short8 fah[4], fbh[4];
#pragma unroll
            for (int i = 0; i < 4; i++) {
                fah[i] = *(const short8*)&sAh[ks][wm * 64 + i * 16 + lr][0];
                fbh[i] = *(const short8*)&sBh[ks][wn * 64 + i * 16 + lr][0];
            }
#pragma unroll
            for (int i = 0; i < 4; i++)
#pragma unroll
                for (int j = 0; j < 4; j++)
                    acc[i][j] = __builtin_amdgcn_mfma_f32_16x16x32_bf16(fah[i], fbh[j], acc[i][j], 0, 0, 0);
        }
        __syncthreads();
    }
    // C/D layout: col = lane&15, row = (lane>>4)*4 + q  [m89-verified]
    int colt = n0 + wn * 64;     // wave-uniform
    int cb = colt & 511;
    if (colt < 512) {
#pragma unroll
        for (int i = 0; i < 4; i++) {
            int mg = m0 + wm * 64 + i * 16 + kh * 4;
#pragma unroll
            for (int j = 0; j < 4; j++) {
                int cg = cb + j * 16 + lr;
#pragma unroll
                for (int q = 0; q < 4; q++)
                    XLb[(size_t)(mg + q) * CH + cg] = bf16rne(acc[i][j][q]);
            }
        }
    } else {
#pragma unroll
        for (int i = 0; i < 4; i++) {
            int mg = m0 + wm * 64 + i * 16 + kh * 4;
#pragma unroll
            for (int j = 0; j < 4; j++) {
                int cg = cb + j * 16 + lr;
#pragma unroll
                for (int q = 0; q < 4; q++)
                    XR[(size_t)(mg + q) * CH + cg] = acc[i][j][q];
            }
        }
    }
}

// ---------- fused per-node: logits + online softmax + aggregation ----------
// r15 structure (node floor: 77% VALUBusy, 12 variants tried, ~63us
// invariant). 2 consecutive nids per 256-thread block; 2 waves per node
// (head-group g); lane l owns 4 consecutive channels g*256+l*4 (one head).
// 3-deep pipeline over 4-edge chunks (idx int4 + gathers in flight).
// Single bf16->f32 convert per value; lrelu = max(t, 0.2t). DPP-only fold;
// per-lane softmax state; defer-rescale THR=8. Tail/pad masked via z=-1e30.

#define GATHER(CX, IV)                                                         \
  {                                                                            \
    CX[0] = *(const u16x4*)(XLg + (size_t)IV[0] * CH);                         \
    CX[1] = *(const u16x4*)(XLg + (size_t)IV[1] * CH);                         \
    CX[2] = *(const u16x4*)(XLg + (size_t)IV[2] * CH);                         \
    CX[3] = *(const u16x4*)(XLg + (size_t)IV[3] * CH);                         \
  }

#define PROCESS(CX, cb)                                                        \
  {                                                                            \
    float f[4][4];                                                             \
    _Pragma("unroll") for (int e = 0; e < 4; e++)                              \
      _Pragma("unroll") for (int r = 0; r < 4; r++)                            \
        f[e][r] = bf16tof(CX[e][r]);                                           \
    float z[4];                                                                \
    _Pragma("unroll") for (int e = 0; e < 4; e++) {                            \
      float s = 0.f;                                                           \
      _Pragma("unroll") for (int r = 0; r < 4; r++) {                          \
        float t = f[e][r] + xrv[r];                                            \
        t = fmaxf(t, NEG * t);                                                 \
        s += t * atv[r];                                                       \
      }                                                                        \
      z[e] = s;                                                                \
    }                                                                          \
    _Pragma("unroll") for (int e = 0; e < 4; e++) {                            \
      z[e] = dpp_add<0xB1>(z[e]);                                              \
      z[e] = dpp_add<0x4E>(z[e]);                                              \
      z[e] = dpp_add<0x124>(z[e]);                                             \
      z[e] = dpp_add<0x128>(z[e]);                                             \
    }                                                                          \
    _Pragma("unroll") for (int e = 1; e < 4; e++)                              \
      if ((cb) + e >= end) z[e] = -1e30f;                                      \
    float mc = fmaxf(fmaxf(z[0], z[1]), fmaxf(z[2], z[3]));                    \
    if (__ballot(mc > mh + 8.f) == 0ULL) {                                     \
      float p0 = __expf(z[0] - mh), p1 = __expf(z[1] - mh);                    \
      float p2 = __expf(z[2] - mh), p3 = __expf(z[3] - mh);                    \
      sh += (p0 + p1) + (p2 + p3);                                             \
      _Pragma("unroll") for (int r = 0; r < 4; r++)                            \
        acc[r] += p0 * f[0][r] + p1 * f[1][r] + p2 * f[2][r] + p3 * f[3][r];   \
    } else {                                                                   \
      float nm = fmaxf(mh, mc);                                                \
      float sc = __expf(mh - nm);                                              \
      float p0 = __expf(z[0] - nm), p1 = __expf(z[1] - nm);                    \
      float p2 = __expf(z[2] - nm), p3 = __expf(z[3] - nm);                    \
      sh = sh * sc + (p0 + p1) + (p2 + p3);                                    \
      mh = nm;                                                                 \
      _Pragma("unroll") for (int r = 0; r < 4; r++)                            \
        acc[r] = acc[r] * sc + p0 * f[0][r] + p1 * f[1][r] + p2 * f[2][r] +    \
                 p3 * f[3][r];                                                 \
    }                                                                          \
  }

template <int WRITE_BF16>
__global__ __launch_bounds__(256) void k_node5(const unsigned short* __restrict__ XLb,
                                               const float* __restrict__ XR,
                                               const int* __restrict__ rowptr,
                                               const int* __restrict__ deg,
                                               const int* __restrict__ ssrc,
                                               const float* __restrict__ att,
                                               const float* __restrict__ bias,
                                               float* __restrict__ OUT,
                                               unsigned short* __restrict__ OAh) {
    int w = threadIdx.x >> 6;
    int nid = blockIdx.x * 2 + (w >> 1);   // global row 0..NT-1
    int g = w & 1;                         // head-group: heads g*4 .. g*4+3
    int l = threadIdx.x & 63;
    int node = nid & (NN - 1);
    int beg = rowptr[node], pend = rowptr[node + 1];
    int end = beg + deg[node];
    int hb = g * 256 + l * 4;              // 4 consecutive channels, one head

    const unsigned short* XLg = XLb + (size_t)(nid >> 13) * NN * CH + hb;
    f32x4 xrv = *(const f32x4*)(XR + (size_t)nid * CH + hb);
    f32x4 atv = *(const f32x4*)(att + hb);
    f32x4 acc = {0.f, 0.f, 0.f, 0.f};
    float mh = -1e30f, sh = 0.f;

    i32x4 iA = *(const i32x4*)(ssrc + beg);
    i32x4 iB = iA;
    u16x4 curA[4], curB[4];
    GATHER(curA, iA);
    if (beg + 4 < pend) iB = *(const i32x4*)(ssrc + beg + 4);

    int base = beg;
    while (true) {
        // invariant: curA = data(c), iB = idx(c+1)
        if (base + 4 < pend) GATHER(curB, iB);
        if (base + 8 < pend) iA = *(const i32x4*)(ssrc + base + 8);
        PROCESS(curA, base);
        base += 4;
        if (base >= pend) break;
        // invariant: curB = data(c'), iA = idx(c'+1)
        if (base + 4 < pend) GATHER(curA, iA);
        if (base + 8 < pend) iB = *(const i32x4*)(ssrc + base + 8);
        PROCESS(curB, base);
        base += 4;
        if (base >= pend) break;
    }

    float inv = 1.f / sh;
    f32x4 biasv = *(const f32x4*)(bias + hb);
    size_t ob = (size_t)nid * CH + hb;
    if (WRITE_BF16) {
        u16x4 hv;
#pragma unroll
        for (int r = 0; r < 4; r++) {
            float wv = acc[r] * inv + biasv[r];
            hv[r] = bf16rne(wv);
        }
        *(u16x4*)(OAh + ob) = hv;
    } else {
        f32x4 ov;
#pragma unroll
        for (int r = 0; r < 4; r++) {
            float wv = acc[r] * inv + biasv[r];
            ov[r] = (wv > 0.f) ? wv : (__expf(wv) - 1.f);
        }
        *(f32x4*)(OUT + ob) = ov;
    }
}

// ---------- host ----------

extern "C" void kernel_launch(void* const* d_in, const int* in_sizes, int n_in,
                              void* d_out, int out_size, void* d_ws, size_t ws_size,
                              hipStream_t stream) {
    const float* x    = (const float*)d_in[0];
    const int*   ei   = (const int*)d_in[1];
    const float* W1l  = (const float*)d_in[2];
    const float* W1r  = (const float*)d_in[3];
    const float* att1 = (const float*)d_in[4];
    const float* b1   = (const float*)d_in[5];
    const float* W2l  = (const float*)d_in[6];
    const float* W2r  = (const float*)d_in[7];
    const float* att2 = (const float*)d_in[8];
    const float* b2   = (const float*)d_in[9];
    float* out = (float*)d_out;

    char* ws = (char*)d_ws;
    int* rowptr = (int*)ws;                 // NN+1
    int* cursor = rowptr + NN + 1;          // NN   (zeroed)
    int* deg    = cursor + NN;              // NN   (zeroed)
    int* ssrc   = deg + NN;                 // SPAD (4-aligned padded)
    unsigned short* XLb = (unsigned short*)(((uintptr_t)(ssrc + SPAD) + 255) & ~(uintptr_t)255);
    float* XR = (float*)(XLb + (size_t)NT * CH);
    unsigned short* A_h = (unsigned short*)(XR + (size_t)NT * CH);  // NT*CH bf16
    unsigned short* W1h = A_h + (size_t)NT * CH;   // 1024*FIN
    unsigned short* W2h = W1h + 1024 * FIN;        // 1024*CH

    hipMemsetAsync(cursor, 0, (size_t)2 * NN * sizeof(int), stream);
    k_deg<<<(EPAD + 255) / 256, 256, 0, stream>>>(ei, deg);
    k_scan<<<1, 1024, 0, stream>>>(deg, rowptr);
    k_scatter<<<(EPAD + 255) / 256, 256, 0, stream>>>(ei, rowptr, cursor, ssrc);
    k_pad<<<NN / 256, 256, 0, stream>>>(rowptr, deg, ssrc);
    k_cvt_w<FIN><<<1024 * FIN / 256, 256, 0, stream>>>(W1l, W1r, W1h);
    k_cvt_w<CH><<<1024 * CH / 256, 256, 0, stream>>>(W2l, W2r, W2h);

    // layer 1 (both batches merged: NT rows)
    k_cvt_ah<<<NT * FIN / 4 / 256, 256, 0, stream>>>(x, A_h, NT * FIN / 4);
    k_gemm_mfma<FIN, 64><<<dim3(NT / 128, 8), 256, 0, stream>>>(A_h, W1h, XLb, XR);
    k_node5<1><<<NT / 2, 256, 0, stream>>>(XLb, XR, rowptr, deg, ssrc, att1, b1, nullptr, A_h);
    // layer 2
    k_gemm_mfma<CH, 64><<<dim3(NT / 128, 8), 256, 0, stream>>>(A_h, W2h, XLb, XR);
    k_node5<0><<<NT / 2, 256, 0, stream>>>(XLb, XR, rowptr, deg, ssrc, att2, b2, out, nullptr);
}